// Round 4
// baseline (135.266 us; speedup 1.0000x reference)
//
#include <hip/hip_runtime.h>
#include <math.h>

// Problem constants
#define HN 8
#define DK 64
#define LQ 4096
#define LKV 1024
#define DMODEL 512
#define BATCH 2

typedef unsigned short u16;
typedef unsigned int u32;
typedef __attribute__((ext_vector_type(8))) __bf16 bf16x8;
typedef __attribute__((ext_vector_type(4))) float f32x4;
typedef __attribute__((ext_vector_type(8))) u16 u16x8;

// fp32 -> bf16 round-to-nearest-even (finite inputs only)
__device__ __forceinline__ u16 f2bf(float f) {
    u32 u = __float_as_uint(f);
    u = u + 0x7fffu + ((u >> 16) & 1u);
    return (u16)(u >> 16);
}
__device__ __forceinline__ float bf2f(u16 u) {
    return __uint_as_float(((u32)u) << 16);
}

// async 16B global -> LDS (per-lane gptr, wave-uniform LDS base; HW writes base + lane*16)
__device__ __forceinline__ void gl_lds16(const u16* g, u16* l) {
    __builtin_amdgcn_global_load_lds((const __attribute__((address_space(1))) u32*)g,
                                     (__attribute__((address_space(3))) u32*)l, 16, 0, 0);
}

// ---------------------------------------------------------------------------
// bf16 MFMA GEMM body: C[M x 512] = A[M x 512] * W, Bt = W^T as [n][k].
// Tile 128(M) x 64(N), BK=32. 4 waves 2x2; each wave 64x32 = 4x2 MFMA tiles.
// Small tile => 768/512-block grids => ~3 blocks/CU so waves hide each
// other's vmcnt(0)+barrier drain (the 1-block/CU regime was the R2 limiter).
// global_load_lds width-16 staging; XOR chunk swizzle -> 2-way aliasing (free).
// ---------------------------------------------------------------------------
template <bool BF16OUT>
__device__ __forceinline__ void gemm_body(const u16* __restrict__ A,
                                          const u16* __restrict__ Bt,
                                          void* __restrict__ Cp,
                                          int bx, int by) {
    __shared__ u16 As[128 * 32];
    __shared__ u16 Bs[64 * 32];

    const int tid = threadIdx.x;
    const int lane = tid & 63;
    const int wave = tid >> 6;
    const int wm = (wave >> 1) * 64;   // wave M offset: 0 or 64
    const int wn = (wave & 1) * 32;    // wave N offset: 0 or 32
    const int quad = lane >> 4;
    const int l16 = lane & 15;
    const size_t m0 = (size_t)by * 128;
    const size_t n0 = (size_t)bx * 64;

    f32x4 acc[4][2] = {};

    for (int k0 = 0; k0 < 512; k0 += 32) {
        // Stage A: 128 rows x 4 chunks = 512 chunks, 2 per thread
#pragma unroll
        for (int i = 0; i < 2; ++i) {
            const int id = i * 256 + tid;
            const int r = id >> 2;
            const int c = (id & 3) ^ ((r >> 1) & 3);
            gl_lds16(&A[(m0 + r) * 512 + k0 + c * 8], &As[(size_t)(i * 256 + wave * 64) * 8]);
        }
        // Stage B: 64 rows x 4 chunks = 256 chunks, 1 per thread
        {
            const int r = tid >> 2;
            const int c = (tid & 3) ^ ((r >> 1) & 3);
            gl_lds16(&Bt[(n0 + r) * 512 + k0 + c * 8], &Bs[(size_t)(wave * 64) * 8]);
        }
        __syncthreads();

        bf16x8 af[4], bfr[2];
#pragma unroll
        for (int i = 0; i < 4; ++i) {
            const int ra = wm + i * 16 + l16;
            const int ca = quad ^ ((ra >> 1) & 3);
            af[i] = *(const bf16x8*)&As[ra * 32 + ca * 8];
        }
#pragma unroll
        for (int j = 0; j < 2; ++j) {
            const int rb = wn + j * 16 + l16;
            const int cb = quad ^ ((rb >> 1) & 3);
            bfr[j] = *(const bf16x8*)&Bs[rb * 32 + cb * 8];
        }
#pragma unroll
        for (int i = 0; i < 4; ++i)
#pragma unroll
            for (int j = 0; j < 2; ++j)
                acc[i][j] = __builtin_amdgcn_mfma_f32_16x16x32_bf16(af[i], bfr[j], acc[i][j], 0, 0, 0);
        __syncthreads();
    }

    // Epilogue: C/D layout col = lane&15, row = quad*4 + reg
#pragma unroll
    for (int i = 0; i < 4; ++i) {
#pragma unroll
        for (int j = 0; j < 2; ++j) {
            const size_t row = m0 + wm + i * 16 + quad * 4;
            const size_t col = n0 + wn + j * 16 + l16;
#pragma unroll
            for (int t = 0; t < 4; ++t) {
                if (BF16OUT)
                    ((u16*)Cp)[(row + t) * 512 + col] = f2bf(acc[i][j][t]);
                else
                    ((float*)Cp)[(row + t) * 512 + col] = acc[i][j][t];
            }
        }
    }
}

// Fused Q/K/V projections, flat 768-block grid (512 Q + 128 K + 128 V), bf16 out.
__global__ __launch_bounds__(256) void proj_fused(const u16* __restrict__ qb,
                                                  const u16* __restrict__ kb,
                                                  const u16* __restrict__ vb,
                                                  const u16* __restrict__ wqt,
                                                  const u16* __restrict__ wkt,
                                                  const u16* __restrict__ wvt,
                                                  u16* __restrict__ Qb,
                                                  u16* __restrict__ Kb,
                                                  u16* __restrict__ Vb) {
    const int idx = blockIdx.x;
    if (idx < 512)
        gemm_body<true>(qb, wqt, Qb, idx & 7, idx >> 3);
    else if (idx < 640)
        gemm_body<true>(kb, wkt, Kb, (idx - 512) & 7, (idx - 512) >> 3);
    else
        gemm_body<true>(vb, wvt, Vb, (idx - 640) & 7, (idx - 640) >> 3);
}

__global__ __launch_bounds__(256) void gemm_out(const u16* __restrict__ A,
                                                const u16* __restrict__ Bt,
                                                float* __restrict__ C) {
    gemm_body<false>(A, Bt, C, blockIdx.x & 7, blockIdx.x >> 3);
}

// ---------------------------------------------------------------------------
// Fused prep: fp32->bf16 converts for q/k/v + transpose-convert of 4 weights.
// ---------------------------------------------------------------------------
__global__ __launch_bounds__(256) void prep(const float* __restrict__ q,
                                            const float* __restrict__ k,
                                            const float* __restrict__ v,
                                            const float* __restrict__ Wq,
                                            const float* __restrict__ Wk,
                                            const float* __restrict__ Wv,
                                            const float* __restrict__ Wout,
                                            u16* __restrict__ qb, u16* __restrict__ kb,
                                            u16* __restrict__ vb,
                                            u16* __restrict__ wqt, u16* __restrict__ wkt,
                                            u16* __restrict__ wvt, u16* __restrict__ wot) {
    __shared__ float tbuf[32][33];
    const int bid = blockIdx.x;
    const int tid = threadIdx.x;

    if (bid < 3072) {
        const float* in;
        u16* outp;
        int i;
        if (bid < 2048)      { in = q; outp = qb; i = bid * 256 + tid; }
        else if (bid < 2560) { in = k; outp = kb; i = (bid - 2048) * 256 + tid; }
        else                 { in = v; outp = vb; i = (bid - 2560) * 256 + tid; }
        const float4 a = ((const float4*)in)[i * 2];
        const float4 b = ((const float4*)in)[i * 2 + 1];
        u16x8 r;
        r[0] = f2bf(a.x); r[1] = f2bf(a.y); r[2] = f2bf(a.z); r[3] = f2bf(a.w);
        r[4] = f2bf(b.x); r[5] = f2bf(b.y); r[6] = f2bf(b.z); r[7] = f2bf(b.w);
        *(u16x8*)&outp[(size_t)i * 8] = r;
    } else {
        const int wb = bid - 3072;
        const int z = wb >> 8;        // which weight
        const int t = wb & 255;       // 16x16 grid of 32x32 tiles
        const float* W = (z == 0) ? Wq : (z == 1) ? Wk : (z == 2) ? Wv : Wout;
        u16* O = (z == 0) ? wqt : (z == 1) ? wkt : (z == 2) ? wvt : wot;
        const int tx = tid & 31;
        const int ty = tid >> 5;      // 0..7
        const int x = (t & 15) * 32 + tx;   // source col n
        const int y0 = (t >> 4) * 32;       // source row k base
#pragma unroll
        for (int i = ty; i < 32; i += 8) tbuf[i][tx] = W[(size_t)(y0 + i) * 512 + x];
        __syncthreads();
#pragma unroll
        for (int i = ty; i < 32; i += 8)
            O[(size_t)((t & 15) * 32 + i) * 512 + y0 + tx] = f2bf(tbuf[tx][i]);
    }
}

// ---------------------------------------------------------------------------
// Sparse sliding-window attention, bf16 inputs, fp32 compute, bf16 ctx out.
// For query c: fd = floor((63-c)/4); KV col(r) = r - fd, valid iff r >= fd.
// ---------------------------------------------------------------------------
__global__ __launch_bounds__(256) void attn_f32(const u16* __restrict__ Q,
                                                const u16* __restrict__ K,
                                                const u16* __restrict__ V,
                                                u16* __restrict__ ctx) {
    __shared__ float Ks[80][68];
    __shared__ float Vs[80][68];

    const int tid = threadIdx.x;
    const int c0 = blockIdx.x * 256;
    const int h = blockIdx.y;
    const int b = blockIdx.z;

    const int fd_c0 = (63 - c0) >> 2;
    const int win_lo = (fd_c0 < 0) ? -fd_c0 : 0;

    for (int i = tid; i < 80 * 8; i += 256) {
        int row = i >> 3;
        int d8 = i & 7;
        int col = win_lo + row;
        if (col < LKV) {
            size_t base = ((size_t)(b * LKV + col)) * DMODEL + h * DK + d8 * 8;
            u16x8 k8 = *(const u16x8*)&K[base];
            u16x8 v8 = *(const u16x8*)&V[base];
            float4 ka = make_float4(bf2f(k8[0]), bf2f(k8[1]), bf2f(k8[2]), bf2f(k8[3]));
            float4 kb4 = make_float4(bf2f(k8[4]), bf2f(k8[5]), bf2f(k8[6]), bf2f(k8[7]));
            float4 va = make_float4(bf2f(v8[0]), bf2f(v8[1]), bf2f(v8[2]), bf2f(v8[3]));
            float4 vb4 = make_float4(bf2f(v8[4]), bf2f(v8[5]), bf2f(v8[6]), bf2f(v8[7]));
            *(float4*)&Ks[row][d8 * 8] = ka;
            *(float4*)&Ks[row][d8 * 8 + 4] = kb4;
            *(float4*)&Vs[row][d8 * 8] = va;
            *(float4*)&Vs[row][d8 * 8 + 4] = vb4;
        }
    }
    __syncthreads();

    const int c = c0 + tid;
    const int fd = (63 - c) >> 2;

    float qreg[64];
    const u16* qp = &Q[((size_t)(b * LQ + c)) * DMODEL + h * DK];
#pragma unroll
    for (int i = 0; i < 8; ++i) {
        u16x8 t8 = *(const u16x8*)&qp[i * 8];
#pragma unroll
        for (int j = 0; j < 8; ++j) qreg[i * 8 + j] = bf2f(t8[j]);
    }

    float sc[16];
    float mx = -3.0e38f;
#pragma unroll
    for (int r = 0; r < 16; ++r) {
        int col = r - fd;
        if (col < 0) col = 0;
        const float* kr = &Ks[col - win_lo][0];
        float s = 0.f;
#pragma unroll
        for (int i = 0; i < 64; ++i) s = fmaf(qreg[i], kr[i], s);
        s *= 0.125f;
        sc[r] = (r >= fd) ? s : -1.0e30f;
        mx = fmaxf(mx, sc[r]);
    }

    float sum = 0.f;
#pragma unroll
    for (int r = 0; r < 16; ++r) {
        sc[r] = __expf(sc[r] - mx);
        sum += sc[r];
    }
    const float inv = 1.0f / sum;

    float acc[64];
#pragma unroll
    for (int i = 0; i < 64; ++i) acc[i] = 0.f;
#pragma unroll
    for (int r = 0; r < 16; ++r) {
        const float w = sc[r] * inv;
        int col = r - fd;
        if (col < 0) col = 0;
        const float* vr = &Vs[col - win_lo][0];
#pragma unroll
        for (int i = 0; i < 64; ++i) acc[i] = fmaf(w, vr[i], acc[i]);
    }

    u16* cp = &ctx[((size_t)(b * LQ + c)) * DMODEL + h * DK];
#pragma unroll
    for (int i = 0; i < 8; ++i) {
        u16x8 o;
#pragma unroll
        for (int j = 0; j < 8; ++j) o[j] = f2bf(acc[i * 8 + j]);
        *(u16x8*)&cp[i * 8] = o;
    }
}

// ---------------------------------------------------------------------------
extern "C" void kernel_launch(void* const* d_in, const int* in_sizes, int n_in,
                              void* d_out, int out_size, void* d_ws, size_t ws_size,
                              hipStream_t stream) {
    const float* q    = (const float*)d_in[0];
    const float* k    = (const float*)d_in[1];
    const float* v    = (const float*)d_in[2];
    const float* Wq   = (const float*)d_in[3];
    const float* Wk   = (const float*)d_in[4];
    const float* Wv   = (const float*)d_in[5];
    const float* Wout = (const float*)d_in[6];
    float* out = (float*)d_out;

    const size_t NQ = (size_t)BATCH * LQ * DMODEL;   // 4,194,304
    const size_t NK = (size_t)BATCH * LKV * DMODEL;  // 1,048,576
    const size_t NW = (size_t)DMODEL * DMODEL;       //   262,144

    // Workspace layout (all bf16 u16)
    u16* qb  = (u16*)d_ws;      // bf16 inputs
    u16* kb  = qb + NQ;
    u16* vb  = kb + NK;
    u16* Qb  = vb + NK;         // bf16 projections
    u16* Kb  = Qb + NQ;
    u16* Vb  = Kb + NK;
    u16* cb  = Vb + NK;         // bf16 ctx
    u16* wqt = cb + NQ;         // bf16 transposed weights
    u16* wkt = wqt + NW;
    u16* wvt = wkt + NW;
    u16* wot = wvt + NW;

    // 1) fused prep: converts + weight transposes
    prep<<<dim3(4096), dim3(256), 0, stream>>>(q, k, v, Wq, Wk, Wv, Wout,
                                               qb, kb, vb, wqt, wkt, wvt, wot);

    // 2) fused Q/K/V projection GEMMs (bf16 MFMA, bf16 out), 128x64 tiles
    proj_fused<<<dim3(768), dim3(256), 0, stream>>>(qb, kb, vb, wqt, wkt, wvt, Qb, Kb, Vb);

    // 3) attention (bf16 in, fp32 compute, bf16 ctx)
    attn_f32<<<dim3(LQ / 256, HN, BATCH), dim3(256), 0, stream>>>(Qb, Kb, Vb, cb);

    // 4) output projection (fp32 out), 128x64 tiles
    gemm_out<<<dim3(512), dim3(256), 0, stream>>>(cb, wot, out);
}

// Round 5
// 133.444 us; speedup vs baseline: 1.0137x; 1.0137x over previous
//
#include <hip/hip_runtime.h>
#include <math.h>

// Problem constants
#define HN 8
#define DK 64
#define LQ 4096
#define LKV 1024
#define DMODEL 512
#define BATCH 2

typedef unsigned short u16;
typedef unsigned int u32;
typedef __attribute__((ext_vector_type(8))) __bf16 bf16x8;
typedef __attribute__((ext_vector_type(4))) float f32x4;
typedef __attribute__((ext_vector_type(8))) u16 u16x8;

// fp32 -> bf16 round-to-nearest-even (finite inputs only)
__device__ __forceinline__ u16 f2bf(float f) {
    u32 u = __float_as_uint(f);
    u = u + 0x7fffu + ((u >> 16) & 1u);
    return (u16)(u >> 16);
}
__device__ __forceinline__ float bf2f(u16 u) {
    return __uint_as_float(((u32)u) << 16);
}

// async 16B global -> LDS (wave-uniform LDS base; HW writes base + lane*16)
__device__ __forceinline__ void gl_lds16(const u16* g, u16* l) {
    __builtin_amdgcn_global_load_lds((const __attribute__((address_space(1))) u32*)g,
                                     (__attribute__((address_space(3))) u32*)l, 16, 0, 0);
}

// ---------------------------------------------------------------------------
// Weight-stationary bf16 MFMA GEMM: C[M x 512] = A[M x 512] * W, Bt = W^T [n][k].
// Block owns a 128-col N-slice: B slice (128x512 bf16 = 128 KB) staged into LDS
// ONCE, then T M-tiles (128 rows each) streamed with double-buffered A chunks
// (BK=32, 8 KB/buf). Prefetch is issued AFTER the barrier so the next barrier's
// vmcnt(0) drain waits on a load issued a full compute-iteration earlier.
// B layout swizzle: physical slot = (kc & ~7) | ((kc ^ rb) & 7)  -> 2-way bank
// aliasing (free) on both staging and fragment reads.
// LDS total: 128 KB (B) + 16 KB (A dbuf) = 147456 B -> 1 block/CU.
// ---------------------------------------------------------------------------
template <bool BF16OUT>
__device__ __forceinline__ void gemm_ws(const u16* __restrict__ A,
                                        const u16* __restrict__ Bt,
                                        void* __restrict__ Cp,
                                        int m0base, int n0, int T,
                                        u16* __restrict__ Bs,   // [128*512]
                                        u16* __restrict__ Asb) {// [2][128*32]
    const int tid = threadIdx.x;
    const int lane = tid & 63;
    const int wave = tid >> 6;
    const int wm = (wave >> 1) * 64;
    const int wn = (wave & 1) * 64;
    const int quad = lane >> 4;
    const int l16 = lane & 15;

    // ---- stage B slice once: 8192 chunks of 16 B, 32 per thread ----
#pragma unroll
    for (int it = 0; it < 32; ++it) {
        const int C = it * 256 + tid;        // chunk index; wave-uniform base (C&~63)
        const int rb = C >> 6;               // B row 0..127 (uniform per wave-op)
        const int s = C & 63;                // physical slot = lane
        const int kc = (s & ~7) | ((s ^ rb) & 7);  // logical k-chunk (XOR swizzle)
        gl_lds16(&Bt[(size_t)(n0 + rb) * 512 + kc * 8], &Bs[(size_t)(C & ~63) * 8]);
    }

    // ---- stage A chunk helper: 512 chunks (128 rows x 4 slots), 2/thread ----
    auto stageA = [&](int m0, int k0, int buf) {
#pragma unroll
        for (int i = 0; i < 2; ++i) {
            const int C = i * 256 + tid;
            const int r = C >> 2;            // row 0..127
            const int s = C & 3;             // k-chunk slot (no swizzle needed)
            gl_lds16(&A[(size_t)(m0 + r) * 512 + k0 + s * 8],
                     &Asb[(size_t)buf * 4096 + (size_t)(C & ~63) * 8]);
        }
    };

    stageA(m0base, 0, 0);
    int buf = 0;

    for (int t = 0; t < T; ++t) {
        const int m0 = m0base + t * 128;
        f32x4 acc[4][4] = {};

        for (int it = 0; it < 16; ++it) {
            __syncthreads();   // drains vmcnt -> A[buf] (and B on first pass) ready
            if (it < 15)
                stageA(m0, (it + 1) * 32, buf ^ 1);
            else if (t + 1 < T)
                stageA(m0 + 128, 0, buf ^ 1);

            bf16x8 af[4], bfr[4];
#pragma unroll
            for (int i = 0; i < 4; ++i) {
                const int ra = wm + i * 16 + l16;
                af[i] = *(const bf16x8*)&Asb[(size_t)buf * 4096 + (size_t)(ra * 4 + quad) * 8];
            }
#pragma unroll
            for (int j = 0; j < 4; ++j) {
                const int rb = wn + j * 16 + l16;
                const int kc = it * 4 + quad;
                const int slot = (kc & ~7) | ((kc ^ rb) & 7);
                bfr[j] = *(const bf16x8*)&Bs[(size_t)(rb * 64 + slot) * 8];
            }
#pragma unroll
            for (int i = 0; i < 4; ++i)
#pragma unroll
                for (int j = 0; j < 4; ++j)
                    acc[i][j] = __builtin_amdgcn_mfma_f32_16x16x32_bf16(af[i], bfr[j], acc[i][j], 0, 0, 0);
            buf ^= 1;
        }

        // Epilogue (overlaps next tile's A[0] prefetch): col = lane&15, row = quad*4+reg
#pragma unroll
        for (int i = 0; i < 4; ++i) {
#pragma unroll
            for (int j = 0; j < 4; ++j) {
                const size_t row = (size_t)m0 + wm + i * 16 + quad * 4;
                const size_t col = (size_t)n0 + wn + j * 16 + l16;
#pragma unroll
                for (int u = 0; u < 4; ++u) {
                    if (BF16OUT)
                        ((u16*)Cp)[(row + u) * 512 + col] = f2bf(acc[i][j][u]);
                    else
                        ((float*)Cp)[(row + u) * 512 + col] = acc[i][j][u];
                }
            }
        }
    }
}

// Fused Q/K/V projections. Flat 256-block grid:
// [0,128): Q jobs (slice = idx&3, 2 M-tiles each); [128,192): K; [192,256): V.
__global__ __launch_bounds__(256) void proj_ws(const u16* __restrict__ qb,
                                               const u16* __restrict__ kb,
                                               const u16* __restrict__ vb,
                                               const u16* __restrict__ wqt,
                                               const u16* __restrict__ wkt,
                                               const u16* __restrict__ wvt,
                                               u16* __restrict__ Qb,
                                               u16* __restrict__ Kb,
                                               u16* __restrict__ Vb) {
    __shared__ u16 Bs[128 * 512];
    __shared__ u16 Asb[2 * 128 * 32];
    const int idx = blockIdx.x;
    if (idx < 128) {
        gemm_ws<true>(qb, wqt, Qb, (idx >> 2) * 256, (idx & 3) * 128, 2, Bs, Asb);
    } else if (idx < 192) {
        const int j = idx - 128;
        gemm_ws<true>(kb, wkt, Kb, (j >> 2) * 128, (j & 3) * 128, 1, Bs, Asb);
    } else {
        const int j = idx - 192;
        gemm_ws<true>(vb, wvt, Vb, (j >> 2) * 128, (j & 3) * 128, 1, Bs, Asb);
    }
}

// Output projection: 256 blocks, 1 M-tile each (slice = idx&3, tile = idx>>2).
__global__ __launch_bounds__(256) void out_ws(const u16* __restrict__ A,
                                              const u16* __restrict__ Bt,
                                              float* __restrict__ C) {
    __shared__ u16 Bs[128 * 512];
    __shared__ u16 Asb[2 * 128 * 32];
    gemm_ws<false>(A, Bt, C, (blockIdx.x >> 2) * 128, (blockIdx.x & 3) * 128, 1, Bs, Asb);
}

// ---------------------------------------------------------------------------
// Fused prep: fp32->bf16 converts for q/k/v + transpose-convert of 4 weights.
// ---------------------------------------------------------------------------
__global__ __launch_bounds__(256) void prep(const float* __restrict__ q,
                                            const float* __restrict__ k,
                                            const float* __restrict__ v,
                                            const float* __restrict__ Wq,
                                            const float* __restrict__ Wk,
                                            const float* __restrict__ Wv,
                                            const float* __restrict__ Wout,
                                            u16* __restrict__ qb, u16* __restrict__ kb,
                                            u16* __restrict__ vb,
                                            u16* __restrict__ wqt, u16* __restrict__ wkt,
                                            u16* __restrict__ wvt, u16* __restrict__ wot) {
    __shared__ float tbuf[32][33];
    const int bid = blockIdx.x;
    const int tid = threadIdx.x;

    if (bid < 3072) {
        const float* in;
        u16* outp;
        int i;
        if (bid < 2048)      { in = q; outp = qb; i = bid * 256 + tid; }
        else if (bid < 2560) { in = k; outp = kb; i = (bid - 2048) * 256 + tid; }
        else                 { in = v; outp = vb; i = (bid - 2560) * 256 + tid; }
        const float4 a = ((const float4*)in)[i * 2];
        const float4 b = ((const float4*)in)[i * 2 + 1];
        u16x8 r;
        r[0] = f2bf(a.x); r[1] = f2bf(a.y); r[2] = f2bf(a.z); r[3] = f2bf(a.w);
        r[4] = f2bf(b.x); r[5] = f2bf(b.y); r[6] = f2bf(b.z); r[7] = f2bf(b.w);
        *(u16x8*)&outp[(size_t)i * 8] = r;
    } else {
        const int wb = bid - 3072;
        const int z = wb >> 8;        // which weight
        const int t = wb & 255;       // 16x16 grid of 32x32 tiles
        const float* W = (z == 0) ? Wq : (z == 1) ? Wk : (z == 2) ? Wv : Wout;
        u16* O = (z == 0) ? wqt : (z == 1) ? wkt : (z == 2) ? wvt : wot;
        const int tx = tid & 31;
        const int ty = tid >> 5;      // 0..7
        const int x = (t & 15) * 32 + tx;   // source col n
        const int y0 = (t >> 4) * 32;       // source row k base
#pragma unroll
        for (int i = ty; i < 32; i += 8) tbuf[i][tx] = W[(size_t)(y0 + i) * 512 + x];
        __syncthreads();
#pragma unroll
        for (int i = ty; i < 32; i += 8)
            O[(size_t)((t & 15) * 32 + i) * 512 + y0 + tx] = f2bf(tbuf[tx][i]);
    }
}

// ---------------------------------------------------------------------------
// Sparse sliding-window attention, bf16 in, fp32 compute, bf16 ctx out.
// 128 queries/block (512 blocks, 2/CU), 48-row K/V window in LDS (26 KB).
// For query c: fd = floor((63-c)/4); KV col(r) = r - fd, valid iff r >= fd.
// ---------------------------------------------------------------------------
__global__ __launch_bounds__(128) void attn_f32(const u16* __restrict__ Q,
                                                const u16* __restrict__ K,
                                                const u16* __restrict__ V,
                                                u16* __restrict__ ctx) {
    __shared__ float Ks[48][68];
    __shared__ float Vs[48][68];

    const int tid = threadIdx.x;
    const int c0 = blockIdx.x * 128;
    const int h = blockIdx.y;
    const int b = blockIdx.z;

    const int fd_c0 = (63 - c0) >> 2;
    const int win_lo = (fd_c0 < 0) ? -fd_c0 : 0;

    for (int i = tid; i < 48 * 8; i += 128) {
        int row = i >> 3;
        int d8 = i & 7;
        int col = win_lo + row;
        if (col < LKV) {
            size_t base = ((size_t)(b * LKV + col)) * DMODEL + h * DK + d8 * 8;
            u16x8 k8 = *(const u16x8*)&K[base];
            u16x8 v8 = *(const u16x8*)&V[base];
            *(float4*)&Ks[row][d8 * 8]     = make_float4(bf2f(k8[0]), bf2f(k8[1]), bf2f(k8[2]), bf2f(k8[3]));
            *(float4*)&Ks[row][d8 * 8 + 4] = make_float4(bf2f(k8[4]), bf2f(k8[5]), bf2f(k8[6]), bf2f(k8[7]));
            *(float4*)&Vs[row][d8 * 8]     = make_float4(bf2f(v8[0]), bf2f(v8[1]), bf2f(v8[2]), bf2f(v8[3]));
            *(float4*)&Vs[row][d8 * 8 + 4] = make_float4(bf2f(v8[4]), bf2f(v8[5]), bf2f(v8[6]), bf2f(v8[7]));
        }
    }
    __syncthreads();

    const int c = c0 + tid;
    const int fd = (63 - c) >> 2;

    float qreg[64];
    const u16* qp = &Q[((size_t)(b * LQ + c)) * DMODEL + h * DK];
#pragma unroll
    for (int i = 0; i < 8; ++i) {
        u16x8 t8 = *(const u16x8*)&qp[i * 8];
#pragma unroll
        for (int j = 0; j < 8; ++j) qreg[i * 8 + j] = bf2f(t8[j]);
    }

    float sc[16];
    float mx = -3.0e38f;
#pragma unroll
    for (int r = 0; r < 16; ++r) {
        int col = r - fd;
        if (col < 0) col = 0;
        const float* kr = &Ks[col - win_lo][0];
        float s = 0.f;
#pragma unroll
        for (int i = 0; i < 64; ++i) s = fmaf(qreg[i], kr[i], s);
        s *= 0.125f;
        sc[r] = (r >= fd) ? s : -1.0e30f;
        mx = fmaxf(mx, sc[r]);
    }

    float sum = 0.f;
#pragma unroll
    for (int r = 0; r < 16; ++r) {
        sc[r] = __expf(sc[r] - mx);
        sum += sc[r];
    }
    const float inv = 1.0f / sum;

    float acc[64];
#pragma unroll
    for (int i = 0; i < 64; ++i) acc[i] = 0.f;
#pragma unroll
    for (int r = 0; r < 16; ++r) {
        const float w = sc[r] * inv;
        int col = r - fd;
        if (col < 0) col = 0;
        const float* vr = &Vs[col - win_lo][0];
#pragma unroll
        for (int i = 0; i < 64; ++i) acc[i] = fmaf(w, vr[i], acc[i]);
    }

    u16* cp = &ctx[((size_t)(b * LQ + c)) * DMODEL + h * DK];
#pragma unroll
    for (int i = 0; i < 8; ++i) {
        u16x8 o;
#pragma unroll
        for (int j = 0; j < 8; ++j) o[j] = f2bf(acc[i * 8 + j]);
        *(u16x8*)&cp[i * 8] = o;
    }
}

// ---------------------------------------------------------------------------
extern "C" void kernel_launch(void* const* d_in, const int* in_sizes, int n_in,
                              void* d_out, int out_size, void* d_ws, size_t ws_size,
                              hipStream_t stream) {
    const float* q    = (const float*)d_in[0];
    const float* k    = (const float*)d_in[1];
    const float* v    = (const float*)d_in[2];
    const float* Wq   = (const float*)d_in[3];
    const float* Wk   = (const float*)d_in[4];
    const float* Wv   = (const float*)d_in[5];
    const float* Wout = (const float*)d_in[6];
    float* out = (float*)d_out;

    const size_t NQ = (size_t)BATCH * LQ * DMODEL;   // 4,194,304
    const size_t NK = (size_t)BATCH * LKV * DMODEL;  // 1,048,576
    const size_t NW = (size_t)DMODEL * DMODEL;       //   262,144

    // Workspace layout (all bf16 u16)
    u16* qb  = (u16*)d_ws;      // bf16 inputs
    u16* kb  = qb + NQ;
    u16* vb  = kb + NK;
    u16* Qb  = vb + NK;         // bf16 projections
    u16* Kb  = Qb + NQ;
    u16* Vb  = Kb + NK;
    u16* cb  = Vb + NK;         // bf16 ctx
    u16* wqt = cb + NQ;         // bf16 transposed weights
    u16* wkt = wqt + NW;
    u16* wvt = wkt + NW;
    u16* wot = wvt + NW;

    // 1) fused prep: converts + weight transposes
    prep<<<dim3(4096), dim3(256), 0, stream>>>(q, k, v, Wq, Wk, Wv, Wout,
                                               qb, kb, vb, wqt, wkt, wvt, wot);

    // 2) fused Q/K/V projections, weight-stationary (bf16 out)
    proj_ws<<<dim3(256), dim3(256), 0, stream>>>(qb, kb, vb, wqt, wkt, wvt, Qb, Kb, Vb);

    // 3) attention (bf16 in, fp32 compute, bf16 ctx)
    attn_f32<<<dim3(LQ / 128, HN, BATCH), dim3(128), 0, stream>>>(Qb, Kb, Vb, cb);

    // 4) output projection, weight-stationary (fp32 out)
    out_ws<<<dim3(256), dim3(256), 0, stream>>>(cb, wot, out);
}